// Round 12
// baseline (1370.244 us; speedup 1.0000x reference)
//
#include <hip/hip_runtime.h>

#define TLEN  1024
#define HN    64
#define NB    16           // batch elements per block -> 64 blocks
#define BROW  104          // h2 row stride (halfs); 208 B, 16B-aligned
#define GPAD  68           // gates_s inner stride (floats): 2-way max on scatter
#define LOG2E 1.4426950408889634f

typedef _Float16 v8h __attribute__((ext_vector_type(8)));
typedef float    v4f __attribute__((ext_vector_type(4)));

// MFMA LSTM v2. 64 blocks x 4 waves; block owns 16 batches (full 16-col
// B-tile -- R6's NB=4 wasted 12/16 cols while paying identical per-wave
// MFMA+activation ISSUE cost). Wave w owns gate w (rows 64w..64w+64).
// Augmented K=96: A = [W_hh | W_ih | b | 0] as 12 f16 A-frags (48 VGPR,
// wave-shared -- no allocator fight; layouts correctness-proven in R6).
// FC fused as a 5th A-tile on wave 0: rows [wfc;0..], 2 extra MFMA compute
// out[b,t-1] from h_{t-1} already in B -- replaces R6's 6 serial shuffles.
// LDS layouts bank-analyzed: gates[4][16][68] scatter b128 2-way/gather b32
// conflict-free (R6's stride-16 layout was 16-32-way: 5.9e7 conflicts).
// Phase2: thread (u=lane, b=4w..4w+3) keeps 4 c's in regs, writes h back
// as f16. x_{t+1} prefetched by wave 3, stored to B cols 64-67.
__global__ __launch_bounds__(256, 1)
void lstm_mfma2(const float* __restrict__ x,      // [B, T, 4]
                const float* __restrict__ W_ih,   // [256, 4]
                const float* __restrict__ W_hh,   // [256, 64]
                const float* __restrict__ b_ih,   // [256]
                const float* __restrict__ b_hh,   // [256]
                const float* __restrict__ W_fc,   // [1, 64]
                const float* __restrict__ b_fc,   // [1]
                float* __restrict__ out)          // [B, T]
{
    const int tid  = threadIdx.x;
    const int w    = tid >> 6;        // wave = gate (i,f,g,o)
    const int lane = tid & 63;
    const int quad = lane >> 4;
    const int col  = lane & 15;       // C col / B n / A m
    const int u    = lane;            // phase-2 hidden unit
    const int b0   = blockIdx.x * NB;

    __shared__ __align__(16) _Float16 h2[NB * BROW];          // B: [n][k]
    __shared__ __align__(16) float gates_s[4 * NB * GPAD];    // [gate][b][u]

    // ---- A-fragments for this wave's gate (f16, scale pre-folded) ----
    const float s = (w == 2) ? 2.0f * LOG2E : LOG2E;   // tanh gate doubled
    v8h a00, a01, a02, a10, a11, a12, a20, a21, a22, a30, a31, a32;
#define LOADA(dst, T, C) { \
        int row = 64 * w + (T) * 16 + col; \
        _Pragma("unroll") \
        for (int j = 0; j < 8; ++j) { \
            int k = (C) * 32 + quad * 8 + j; \
            float v; \
            if (k < 64)       v = W_hh[row * 64 + k]; \
            else if (k < 68)  v = W_ih[row * 4 + (k - 64)]; \
            else if (k == 68) v = b_ih[row] + b_hh[row]; \
            else              v = 0.0f; \
            dst[j] = (_Float16)(v * s); \
        } }
    LOADA(a00, 0, 0) LOADA(a01, 0, 1) LOADA(a02, 0, 2)
    LOADA(a10, 1, 0) LOADA(a11, 1, 1) LOADA(a12, 1, 2)
    LOADA(a20, 2, 0) LOADA(a21, 2, 1) LOADA(a22, 2, 2)
    LOADA(a30, 3, 0) LOADA(a31, 3, 1) LOADA(a32, 3, 2)
#undef LOADA

    // FC A-tile: row 0 = wfc (k<64), rest 0. Only lanes col==0 hold data.
    v8h fc0, fc1;
#pragma unroll
    for (int j = 0; j < 8; ++j) {
        fc0[j] = (col == 0) ? (_Float16)W_fc[quad * 8 + j]      : (_Float16)0.0f;
        fc1[j] = (col == 0) ? (_Float16)W_fc[32 + quad * 8 + j] : (_Float16)0.0f;
    }
    const float bfc = b_fc[0];

    // ---- init: zero h2 (h_{-1}=0, pad cols 0), x_0, bias-one column ----
    for (int i = tid; i < (NB * BROW) / 2; i += 256)
        ((unsigned int*)h2)[i] = 0u;
    __syncthreads();
    if (tid < 64)   // x_0 into cols 64..67
        h2[(tid >> 2) * BROW + 64 + (tid & 3)] =
            (_Float16)x[((size_t)(b0 + (tid >> 2))) * TLEN * 4 + (tid & 3)];
    if (tid < NB)   // bias column k=68
        h2[tid * BROW + 68] = (_Float16)1.0f;
    __syncthreads();

    float c0 = 0.f, c1 = 0.f, c2 = 0.f, c3 = 0.f;   // c[u, 4w+i]

    for (int t = 0; t < TLEN; ++t) {
        // x_{t+1} prefetch (wave 3), consumed end of phase 2
        float xv = 0.0f;
        if (w == 3) {
            int tn = (t + 1 < TLEN) ? t + 1 : TLEN - 1;
            xv = x[((size_t)(b0 + (lane >> 2))) * TLEN * 4
                   + (size_t)tn * 4 + (lane & 3)];
        }

        // ---- Phase 1: B-frags + 12 MFMA (+2 FC on wave 0) ----
        const v8h bf0 = *(const v8h*)(h2 + col * BROW +  0 + quad * 8);
        const v8h bf1 = *(const v8h*)(h2 + col * BROW + 32 + quad * 8);
        const v8h bf2 = *(const v8h*)(h2 + col * BROW + 64 + quad * 8);

        v4f ac0 = {0.f,0.f,0.f,0.f}, ac1 = {0.f,0.f,0.f,0.f};
        v4f ac2 = {0.f,0.f,0.f,0.f}, ac3 = {0.f,0.f,0.f,0.f};
        ac0 = __builtin_amdgcn_mfma_f32_16x16x32_f16(a00, bf0, ac0, 0, 0, 0);
        ac1 = __builtin_amdgcn_mfma_f32_16x16x32_f16(a10, bf0, ac1, 0, 0, 0);
        ac2 = __builtin_amdgcn_mfma_f32_16x16x32_f16(a20, bf0, ac2, 0, 0, 0);
        ac3 = __builtin_amdgcn_mfma_f32_16x16x32_f16(a30, bf0, ac3, 0, 0, 0);
        ac0 = __builtin_amdgcn_mfma_f32_16x16x32_f16(a01, bf1, ac0, 0, 0, 0);
        ac1 = __builtin_amdgcn_mfma_f32_16x16x32_f16(a11, bf1, ac1, 0, 0, 0);
        ac2 = __builtin_amdgcn_mfma_f32_16x16x32_f16(a21, bf1, ac2, 0, 0, 0);
        ac3 = __builtin_amdgcn_mfma_f32_16x16x32_f16(a31, bf1, ac3, 0, 0, 0);
        ac0 = __builtin_amdgcn_mfma_f32_16x16x32_f16(a02, bf2, ac0, 0, 0, 0);
        ac1 = __builtin_amdgcn_mfma_f32_16x16x32_f16(a12, bf2, ac1, 0, 0, 0);
        ac2 = __builtin_amdgcn_mfma_f32_16x16x32_f16(a22, bf2, ac2, 0, 0, 0);
        ac3 = __builtin_amdgcn_mfma_f32_16x16x32_f16(a32, bf2, ac3, 0, 0, 0);

        if (w == 0) {   // FC of h_{t-1} -> out[b, t-1]
            v4f fa = {0.f,0.f,0.f,0.f};
            fa = __builtin_amdgcn_mfma_f32_16x16x32_f16(fc0, bf0, fa, 0, 0, 0);
            fa = __builtin_amdgcn_mfma_f32_16x16x32_f16(fc1, bf1, fa, 0, 0, 0);
            if (t > 0 && quad == 0)
                out[((size_t)(b0 + col)) * TLEN + (t - 1)] = fa[0] + bfc;
        }

        // ---- activation (wave-uniform fn) + b128 scatter ----
#define ACT(a) ((w == 2) \
        ? (1.0f - 2.0f * __builtin_amdgcn_rcpf(1.0f + __builtin_amdgcn_exp2f(a))) \
        : __builtin_amdgcn_rcpf(1.0f + __builtin_amdgcn_exp2f(-(a))))
#define STORE_TILE(acc, T) { \
        float4 av = make_float4(ACT(acc[0]), ACT(acc[1]), \
                                ACT(acc[2]), ACT(acc[3])); \
        *(float4*)&gates_s[w * (NB * GPAD) + col * GPAD \
                           + (T) * 16 + quad * 4] = av; }
        STORE_TILE(ac0, 0)
        STORE_TILE(ac1, 1)
        STORE_TILE(ac2, 2)
        STORE_TILE(ac3, 3)
#undef STORE_TILE
#undef ACT
        __syncthreads();

        // ---- Phase 2: thread (u, b=4w+i), c in regs ----
#define UPD(i, cc) { \
        int b = 4 * w + (i); \
        float gi = gates_s[0 * (NB * GPAD) + b * GPAD + u]; \
        float gf = gates_s[1 * (NB * GPAD) + b * GPAD + u]; \
        float gg = gates_s[2 * (NB * GPAD) + b * GPAD + u]; \
        float go = gates_s[3 * (NB * GPAD) + b * GPAD + u]; \
        cc = gf * cc + gi * gg; \
        float th = 1.0f - 2.0f * __builtin_amdgcn_rcpf( \
                       1.0f + __builtin_amdgcn_exp2f(cc * (2.0f * LOG2E))); \
        h2[b * BROW + u] = (_Float16)(go * th); }
        UPD(0, c0)
        UPD(1, c1)
        UPD(2, c2)
        UPD(3, c3)
#undef UPD
        if (w == 3)   // x_{t+1} into B cols 64..67
            h2[(lane >> 2) * BROW + 64 + (lane & 3)] = (_Float16)xv;
        __syncthreads();
    }

    // ---- epilogue: out[b, 1023] from h_1023 ----
    if (w == 0) {
        const v8h bf0 = *(const v8h*)(h2 + col * BROW +  0 + quad * 8);
        const v8h bf1 = *(const v8h*)(h2 + col * BROW + 32 + quad * 8);
        v4f fa = {0.f,0.f,0.f,0.f};
        fa = __builtin_amdgcn_mfma_f32_16x16x32_f16(fc0, bf0, fa, 0, 0, 0);
        fa = __builtin_amdgcn_mfma_f32_16x16x32_f16(fc1, bf1, fa, 0, 0, 0);
        if (quad == 0)
            out[((size_t)(b0 + col)) * TLEN + (TLEN - 1)] = fa[0] + bfc;
    }
}

extern "C" void kernel_launch(void* const* d_in, const int* in_sizes, int n_in,
                              void* d_out, int out_size, void* d_ws, size_t ws_size,
                              hipStream_t stream) {
    const float* x    = (const float*)d_in[0];
    const float* W_ih = (const float*)d_in[1];
    const float* W_hh = (const float*)d_in[2];
    const float* b_ih = (const float*)d_in[3];
    const float* b_hh = (const float*)d_in[4];
    const float* W_fc = (const float*)d_in[5];
    const float* b_fc = (const float*)d_in[6];
    float* out = (float*)d_out;

    const int B = in_sizes[0] / (TLEN * 4);   // 1024
    lstm_mfma2<<<dim3(B / NB), dim3(256), 0, stream>>>(
        x, W_ih, W_hh, b_ih, b_hh, W_fc, b_fc, out);
}

// Round 13
// 1006.492 us; speedup vs baseline: 1.3614x; 1.3614x over previous
//
#include <hip/hip_runtime.h>

#define TLEN  1024
#define HN    64
#define LOG2E 1.4426950408889634f

// clang builtins (cvt_pkrtz / fdot2) take __fp16 vectors, not _Float16 (R7).
typedef __fp16 half2v __attribute__((ext_vector_type(2)));

// 2-wave k-split dot2 LSTM. Block = 128 thr (2 waves) per batch element;
// grid 1024 -> 4 blocks/CU = 2 waves/SIMD (the latency hiding R8-R11's
// 1-wave designs never had). Lane g of wave w owns hidden unit g's 4 gate
// rows restricted to k-pairs {j, j+32}, j in [16w,16w+16): 64 half2 weight
// VGPRs -- under the allocator's ~64-reg spill threshold (R6: 48 ok;
// R8: 128 spilled to scratch; R11: AGPR reads serialized). v_dot2_f32_f16 =
// 2 MACs/instr, fp32 acc. h broadcast: hp = cvt_pkrtz(h, shfl_down(h,32));
// wave w readlanes j=16w..16w+15 only. Partial exchange: float4 through
// double-buffered LDS, ONE barrier/step (R5-proven safe + bitwise-identical
// redundant update in both waves). Wave 1 owns x.W_ih + FC ring + store;
// wave 0 owns biases. log2e pre-folded (2x for tanh gate).

#define FOR16(X) \
    X(0) X(1) X(2) X(3) X(4) X(5) X(6) X(7) \
    X(8) X(9) X(10) X(11) X(12) X(13) X(14) X(15)

__global__ __launch_bounds__(128)
__attribute__((amdgpu_waves_per_eu(2, 2)))
void lstm_ks(const float* __restrict__ x,      // [B, T, 4]
             const float* __restrict__ W_ih,   // [256, 4]
             const float* __restrict__ W_hh,   // [256, 64]
             const float* __restrict__ b_ih,   // [256]
             const float* __restrict__ b_hh,   // [256]
             const float* __restrict__ W_fc,   // [1, 64]
             const float* __restrict__ b_fc,   // [1]
             float* __restrict__ out)          // [B, T]
{
    const int tid = threadIdx.x;
    const int g   = tid & 63;        // hidden unit 0..63
    const int w   = tid >> 6;        // wave 0/1 = k-half
    const int b   = blockIdx.x;
    const int jb  = 16 * w;          // readlane base

    __shared__ __align__(16) float4 px[2][2][HN];   // partial exchange, dbuf
    __shared__ float ring[64][65];                  // FC partials (bank-free)

    const float* wr_i = W_hh + (0 * HN + g) * HN;
    const float* wr_f = W_hh + (1 * HN + g) * HN;
    const float* wr_g = W_hh + (2 * HN + g) * HN;
    const float* wr_o = W_hh + (3 * HN + g) * HN;

    // ---- 64 packed weight pairs {k=jb+m, k=jb+m+32}, pre-scaled ----
#define DECL(m) half2v qi##m, qf##m, qg##m, qo##m;
    FOR16(DECL)
#undef DECL

#define LOADW(m) \
    qi##m = __builtin_amdgcn_cvt_pkrtz(wr_i[jb + m] * LOG2E, \
                                       wr_i[jb + m + 32] * LOG2E); \
    qf##m = __builtin_amdgcn_cvt_pkrtz(wr_f[jb + m] * LOG2E, \
                                       wr_f[jb + m + 32] * LOG2E); \
    qg##m = __builtin_amdgcn_cvt_pkrtz(wr_g[jb + m] * (2.0f * LOG2E), \
                                       wr_g[jb + m + 32] * (2.0f * LOG2E)); \
    qo##m = __builtin_amdgcn_cvt_pkrtz(wr_o[jb + m] * LOG2E, \
                                       wr_o[jb + m + 32] * LOG2E); \
    asm volatile("" : "+v"(qi##m), "+v"(qf##m), "+v"(qg##m), "+v"(qo##m));
    FOR16(LOADW)
#undef LOADW

    // wave 0: biases; wave 1: x-weights (2 pairs/gate), all pre-scaled
    float bias_i = 0.f, bias_f = 0.f, bias_g = 0.f, bias_o = 0.f;
    half2v xi0 = {0, 0}, xi1 = {0, 0}, xf0 = {0, 0}, xf1 = {0, 0};
    half2v xg0 = {0, 0}, xg1 = {0, 0}, xo0 = {0, 0}, xo1 = {0, 0};
    if (w == 0) {
        bias_i = (b_ih[0 * HN + g] + b_hh[0 * HN + g]) * LOG2E;
        bias_f = (b_ih[1 * HN + g] + b_hh[1 * HN + g]) * LOG2E;
        bias_g = (b_ih[2 * HN + g] + b_hh[2 * HN + g]) * (2.0f * LOG2E);
        bias_o = (b_ih[3 * HN + g] + b_hh[3 * HN + g]) * LOG2E;
    } else {
        const float* pI = W_ih + (0 * HN + g) * 4;
        const float* pF = W_ih + (1 * HN + g) * 4;
        const float* pG = W_ih + (2 * HN + g) * 4;
        const float* pO = W_ih + (3 * HN + g) * 4;
        xi0 = __builtin_amdgcn_cvt_pkrtz(pI[0] * LOG2E, pI[1] * LOG2E);
        xi1 = __builtin_amdgcn_cvt_pkrtz(pI[2] * LOG2E, pI[3] * LOG2E);
        xf0 = __builtin_amdgcn_cvt_pkrtz(pF[0] * LOG2E, pF[1] * LOG2E);
        xf1 = __builtin_amdgcn_cvt_pkrtz(pF[2] * LOG2E, pF[3] * LOG2E);
        xg0 = __builtin_amdgcn_cvt_pkrtz(pG[0] * 2.0f * LOG2E, pG[1] * 2.0f * LOG2E);
        xg1 = __builtin_amdgcn_cvt_pkrtz(pG[2] * 2.0f * LOG2E, pG[3] * 2.0f * LOG2E);
        xo0 = __builtin_amdgcn_cvt_pkrtz(pO[0] * LOG2E, pO[1] * LOG2E);
        xo1 = __builtin_amdgcn_cvt_pkrtz(pO[2] * LOG2E, pO[3] * LOG2E);
    }
    const float wfc = W_fc[g];
    const float bfc = b_fc[0];

    const float* xb = x   + (size_t)b * TLEN * 4;
    float*       ob = out + (size_t)b * TLEN;

    float h = 0.0f, c = 0.0f;
    int hp = 0;   // packed {h[j], h[j+32]} per lane j (h starts 0)
    half2v xp0 = {0, 0}, xp1 = {0, 0};
    if (w == 1) {
        float4 x0 = *(const float4*)(xb);
        xp0 = __builtin_amdgcn_cvt_pkrtz(x0.x, x0.y);
        xp1 = __builtin_amdgcn_cvt_pkrtz(x0.z, x0.w);
    }

    for (int t = 0; t < TLEN; ++t) {
        float4 xn = {0, 0, 0, 0};
        if (w == 1) {
            int tn = t + 1; if (tn >= TLEN) tn = TLEN - 1;
            xn = *(const float4*)(xb + (size_t)tn * 4);   // prefetch
        }

        // ---- partial dots: wave0 = bias + k{0..15,32..47};
        //                    wave1 = x.W_ih + k{16..31,48..63} ----
        float pi, pf, pg, po;
        if (w == 0) {
            pi = bias_i; pf = bias_f; pg = bias_g; po = bias_o;
        } else {
            pi = __builtin_amdgcn_fdot2(xi0, xp0, 0.0f, false);
            pf = __builtin_amdgcn_fdot2(xf0, xp0, 0.0f, false);
            pg = __builtin_amdgcn_fdot2(xg0, xp0, 0.0f, false);
            po = __builtin_amdgcn_fdot2(xo0, xp0, 0.0f, false);
            pi = __builtin_amdgcn_fdot2(xi1, xp1, pi, false);
            pf = __builtin_amdgcn_fdot2(xf1, xp1, pf, false);
            pg = __builtin_amdgcn_fdot2(xg1, xp1, pg, false);
            po = __builtin_amdgcn_fdot2(xo1, xp1, po, false);
        }
#define MAC(m) { \
        int hj = __builtin_amdgcn_readlane(hp, jb + (m)); \
        half2v hh = __builtin_bit_cast(half2v, hj); \
        pi = __builtin_amdgcn_fdot2(qi##m, hh, pi, false); \
        pf = __builtin_amdgcn_fdot2(qf##m, hh, pf, false); \
        pg = __builtin_amdgcn_fdot2(qg##m, hh, pg, false); \
        po = __builtin_amdgcn_fdot2(qo##m, hh, po, false); }
        FOR16(MAC)
#undef MAC

        // ---- exchange (dbuf, 1 barrier); commutative add -> identical h ----
        px[t & 1][w][g] = make_float4(pi, pf, pg, po);
        __syncthreads();
        float4 oth = px[t & 1][1 - w][g];
        float ai = pi + oth.x;
        float af = pf + oth.y;
        float ag = pg + oth.z;
        float ao = po + oth.w;

        // ---- activations (pre-scaled): sigmoid/tanh via exp2+rcp ----
        float si = __builtin_amdgcn_rcpf(1.0f + __builtin_amdgcn_exp2f(-ai));
        float sf = __builtin_amdgcn_rcpf(1.0f + __builtin_amdgcn_exp2f(-af));
        float tg = 1.0f - 2.0f * __builtin_amdgcn_rcpf(
                                     1.0f + __builtin_amdgcn_exp2f(ag));
        float so = __builtin_amdgcn_rcpf(1.0f + __builtin_amdgcn_exp2f(-ao));

        c = sf * c + si * tg;
        float th = 1.0f - 2.0f * __builtin_amdgcn_rcpf(
                       1.0f + __builtin_amdgcn_exp2f(c * (2.0f * LOG2E)));
        h = so * th;

        // repack h pairs for next step's readlane broadcast (both waves)
        float h_hi = __shfl_down(h, 32, 64);
        hp = __builtin_bit_cast(int, __builtin_amdgcn_cvt_pkrtz(h, h_hi));

        // ---- wave 1: x repack + FC ring + periodic coalesced store ----
        if (w == 1) {
            xp0 = __builtin_amdgcn_cvt_pkrtz(xn.x, xn.y);
            xp1 = __builtin_amdgcn_cvt_pkrtz(xn.z, xn.w);
            ring[t & 63][g] = h * wfc;
            if ((t & 63) == 63) {   // own-wave data: lgkmcnt orders w->r
                float s0 = 0.f, s1 = 0.f, s2 = 0.f, s3 = 0.f;
#pragma unroll
                for (int k = 0; k < HN; k += 4) {
                    s0 += ring[g][k];
                    s1 += ring[g][k + 1];
                    s2 += ring[g][k + 2];
                    s3 += ring[g][k + 3];
                }
                ob[(t - 63) + g] = (s0 + s1) + (s2 + s3) + bfc;
            }
        }
    }
}

extern "C" void kernel_launch(void* const* d_in, const int* in_sizes, int n_in,
                              void* d_out, int out_size, void* d_ws, size_t ws_size,
                              hipStream_t stream) {
    const float* x    = (const float*)d_in[0];
    const float* W_ih = (const float*)d_in[1];
    const float* W_hh = (const float*)d_in[2];
    const float* b_ih = (const float*)d_in[3];
    const float* b_hh = (const float*)d_in[4];
    const float* W_fc = (const float*)d_in[5];
    const float* b_fc = (const float*)d_in[6];
    float* out = (float*)d_out;

    const int B = in_sizes[0] / (TLEN * 4);   // 1024
    lstm_ks<<<dim3(B), dim3(128), 0, stream>>>(
        x, W_ih, W_hh, b_ih, b_hh, W_fc, b_fc, out);
}